// Round 1
// baseline (341.518 us; speedup 1.0000x reference)
//
#include <hip/hip_runtime.h>
#include <hip/hip_bf16.h>
#include <stdint.h>

// KQV_28956669510232: out = softmax((x@Wq)(x@Wk)^T / 32, axis=keys) @ (x@Wv)
// B=4, S=2048, D=1024, fp32 in/out. Strategy: bf16 MFMA for all GEMMs
// (threshold 5.86e-3 is bf16-floor), materialized scores in ws.
//
// ws layout (needs ~150 MB):
//   xb     bf16 [8192][1024]          @ 0         (16 MB)
//   wt     bf16 [3072][1024] (W^T)    @ 16777216  (6 MB)   rows: q(0..1023) k(1024..) v(2048..)
//   bc     f32  [3072]                @ 23068672
//   qkv    bf16 [8192][3072]          @ 23080960  (48 MB)
//   vT     bf16 [4][1024][2048]       @ 73412608  (16 MB)
//   sc     f32  [4][2048][2048]       @ 90189824  (64 MB)  -> P bf16 in-place, row pitch 4096 elems

typedef unsigned short u16;
typedef __bf16 bf16x8 __attribute__((ext_vector_type(8)));
typedef float  f32x4  __attribute__((ext_vector_type(4)));
typedef u16    u16x4  __attribute__((ext_vector_type(4)));
typedef u16    u16x8  __attribute__((ext_vector_type(8)));

__device__ __forceinline__ u16 f2bf(float f) {
  union { float f; uint32_t u; } v; v.f = f;
  uint32_t r = v.u + 0x7fffu + ((v.u >> 16) & 1u);   // RNE
  return (u16)(r >> 16);
}

#define GLD_LDS16(gp, lp) __builtin_amdgcn_global_load_lds(                   \
    (const __attribute__((address_space(1))) void*)(gp),                      \
    (__attribute__((address_space(3))) void*)(lp), 16, 0, 0)

// ---------------- converts ----------------

__global__ __launch_bounds__(256) void conv_x(const float* __restrict__ in,
                                              u16* __restrict__ out, int n) {
  int i = (blockIdx.x * 256 + threadIdx.x) * 4;
  if (i >= n) return;
  float4 v = *(const float4*)(in + i);
  u16x4 o; o.x = f2bf(v.x); o.y = f2bf(v.y); o.z = f2bf(v.z); o.w = f2bf(v.w);
  *(u16x4*)(out + i) = o;
}

// W [1024][1024] f32 row-major -> Wt [1024][1024] bf16 with Wt[e][d] = W[d][e]
__global__ __launch_bounds__(256) void trans_conv_w(const float* __restrict__ W,
                                                    u16* __restrict__ Wt) {
  __shared__ float t[32][33];
  int e0 = blockIdx.x * 32, d0 = blockIdx.y * 32;
  #pragma unroll
  for (int i = 0; i < 4; ++i)
    t[threadIdx.y + i * 8][threadIdx.x] =
        W[(size_t)(d0 + threadIdx.y + i * 8) * 1024 + e0 + threadIdx.x];
  __syncthreads();
  #pragma unroll
  for (int i = 0; i < 4; ++i)
    Wt[(size_t)(e0 + threadIdx.y + i * 8) * 1024 + d0 + threadIdx.x] =
        f2bf(t[threadIdx.x][threadIdx.y + i * 8]);
}

__global__ __launch_bounds__(256) void concat_bias(const float* __restrict__ bq,
                                                   const float* __restrict__ bk,
                                                   const float* __restrict__ bv,
                                                   float* __restrict__ bc) {
  int i = blockIdx.x * 256 + threadIdx.x;
  if (i >= 3072) return;
  bc[i] = (i < 1024) ? bq[i] : (i < 2048 ? bk[i - 1024] : bv[i - 2048]);
}

// v part of qkv [b*2048+s][2048+e] -> vT[b][e][s]
__global__ __launch_bounds__(256) void trans_v(const u16* __restrict__ qkv,
                                               u16* __restrict__ vT) {
  __shared__ u16 t[32][33];
  int b = blockIdx.z;
  int s0 = blockIdx.x * 32, e0 = blockIdx.y * 32;
  const u16* src = qkv + (size_t)b * 2048 * 3072 + 2048;
  u16* dst = vT + (size_t)b * 1024 * 2048;
  #pragma unroll
  for (int i = 0; i < 4; ++i)
    t[threadIdx.y + i * 8][threadIdx.x] =
        src[(size_t)(s0 + threadIdx.y + i * 8) * 3072 + e0 + threadIdx.x];
  __syncthreads();
  #pragma unroll
  for (int i = 0; i < 4; ++i)
    dst[(size_t)(e0 + threadIdx.y + i * 8) * 2048 + s0 + threadIdx.x] =
        t[threadIdx.x][threadIdx.y + i * 8];
}

// ---------------- BT GEMM: C[m][n] = scale * sum_k A[m][k]*B[n][k] (+bias[n]) --------
// 128x128 tile, BK=32, 256 threads = 4 waves (2x2 of 64x64), 16x16x32 bf16 MFMA.
// m97 structure: global_load_lds width-16 staging, single-buffered LDS.

template <bool OUT_BF16, bool BIAS>
__global__ __launch_bounds__(256)
void gemm_bt(const u16* __restrict__ A, int lda, long long sA,
             const u16* __restrict__ B, int ldb, long long sB,
             void* __restrict__ C, int ldc, long long sC,
             const float* __restrict__ bias, int K, float scale) {
  __shared__ u16 As[128 * 32];
  __shared__ u16 Bs[128 * 32];
  const int lane = threadIdx.x & 63;
  const int wv = threadIdx.x >> 6;

  const u16* Ab = A + (size_t)blockIdx.z * sA + (size_t)blockIdx.y * 128 * lda;
  const u16* Bb = B + (size_t)blockIdx.z * sB + (size_t)blockIdx.x * 128 * ldb;

  const int srow = lane >> 2;          // staging: 4 lanes per 64B row-chunk
  const int scol = (lane & 3) * 8;     // element offset (8 bf16 = 16B)
  const int frow = lane & 15;          // fragment row/col within 16
  const int fk = (lane >> 4) * 8;      // fragment k offset
  const int wm = (wv >> 1) * 64;       // wave tile origin in 128x128
  const int wn = (wv & 1) * 64;

  f32x4 acc[4][4];
  #pragma unroll
  for (int i = 0; i < 4; ++i)
    #pragma unroll
    for (int j = 0; j < 4; ++j) acc[i][j] = (f32x4)0.0f;

  for (int k0 = 0; k0 < K; k0 += 32) {
    // stage A and B tiles: each wave covers 32 rows (2 calls x 16 rows)
    #pragma unroll
    for (int i = 0; i < 2; ++i) {
      int r = wv * 32 + i * 16;  // wave-uniform
      GLD_LDS16(Ab + (size_t)(r + srow) * lda + k0 + scol, As + r * 32);
      GLD_LDS16(Bb + (size_t)(r + srow) * ldb + k0 + scol, Bs + r * 32);
    }
    __syncthreads();

    bf16x8 af[4], bfr[4];
    #pragma unroll
    for (int i = 0; i < 4; ++i) {
      af[i] = *(const bf16x8*)(As + (wm + i * 16 + frow) * 32 + fk);
      bfr[i] = *(const bf16x8*)(Bs + (wn + i * 16 + frow) * 32 + fk);
    }
    #pragma unroll
    for (int i = 0; i < 4; ++i)
      #pragma unroll
      for (int j = 0; j < 4; ++j)
        acc[i][j] = __builtin_amdgcn_mfma_f32_16x16x32_bf16(af[i], bfr[j], acc[i][j], 0, 0, 0);
    __syncthreads();
  }

  // epilogue: C/D layout col=lane&15, row=(lane>>4)*4+reg  [m89-verified]
  const int quad = lane >> 4;
  const int crow = blockIdx.y * 128 + wm + quad * 4;
  const int ccol = blockIdx.x * 128 + wn + (lane & 15);
  u16* Cb = (u16*)C + (size_t)blockIdx.z * sC;
  float* Cf = (float*)C + (size_t)blockIdx.z * sC;
  #pragma unroll
  for (int i = 0; i < 4; ++i) {
    #pragma unroll
    for (int r = 0; r < 4; ++r) {
      int m = crow + i * 16 + r;
      #pragma unroll
      for (int j = 0; j < 4; ++j) {
        int n = ccol + j * 16;
        float v = acc[i][j][r] * scale;
        if (BIAS) v += bias[n];
        if (OUT_BF16) Cb[(size_t)m * ldc + n] = f2bf(v);
        else          Cf[(size_t)m * ldc + n] = v;
      }
    }
  }
}

// ---------------- softmax over rows of 2048 f32, write bf16 P in place -------------

__global__ __launch_bounds__(256) void softmax_rows(float* __restrict__ S) {
  __shared__ float red[4];
  const int t = threadIdx.x;
  const int lane = t & 63, wv = t >> 6;
  float* row = S + (size_t)blockIdx.x * 2048;
  const float4* rv = (const float4*)row;
  float4 a = rv[t * 2], b = rv[t * 2 + 1];
  float v[8] = {a.x, a.y, a.z, a.w, b.x, b.y, b.z, b.w};
  float m = v[0];
  #pragma unroll
  for (int j = 1; j < 8; ++j) m = fmaxf(m, v[j]);
  #pragma unroll
  for (int off = 32; off > 0; off >>= 1) m = fmaxf(m, __shfl_down(m, off));
  if (lane == 0) red[wv] = m;
  __syncthreads();
  m = fmaxf(fmaxf(red[0], red[1]), fmaxf(red[2], red[3]));
  __syncthreads();
  float e[8], s = 0.f;
  #pragma unroll
  for (int j = 0; j < 8; ++j) { e[j] = exp2f((v[j] - m) * 1.44269504f); s += e[j]; }
  #pragma unroll
  for (int off = 32; off > 0; off >>= 1) s += __shfl_down(s, off);
  if (lane == 0) red[wv] = s;
  __syncthreads();
  s = red[0] + red[1] + red[2] + red[3];
  float inv = 1.0f / s;
  u16x8 w;
  #pragma unroll
  for (int j = 0; j < 8; ++j) w[j] = f2bf(e[j] * inv);
  ((u16x8*)row)[t] = w;   // all reads happened before the barriers above
}

// ---------------- launch ----------------

extern "C" void kernel_launch(void* const* d_in, const int* in_sizes, int n_in,
                              void* d_out, int out_size, void* d_ws, size_t ws_size,
                              hipStream_t stream) {
  const float* x  = (const float*)d_in[0];
  const float* Wk = (const float*)d_in[1];
  const float* bk = (const float*)d_in[2];
  const float* Wq = (const float*)d_in[3];
  const float* bq = (const float*)d_in[4];
  const float* Wv = (const float*)d_in[5];
  const float* bv = (const float*)d_in[6];
  float* out = (float*)d_out;

  char* ws = (char*)d_ws;
  u16*   xb  = (u16*)(ws + 0);
  u16*   wt  = (u16*)(ws + 16777216);
  float* bc  = (float*)(ws + 23068672);
  u16*   qkv = (u16*)(ws + 23080960);
  u16*   vT  = (u16*)(ws + 73412608);
  float* sc  = (float*)(ws + 90189824);
  (void)in_sizes; (void)n_in; (void)out_size; (void)ws_size;

  // 1. convert inputs to bf16 (W transposed so every GEMM is BT-form)
  conv_x<<<8192, 256, 0, stream>>>(x, xb, 8388608);
  trans_conv_w<<<dim3(32, 32), dim3(32, 8), 0, stream>>>(Wq, wt);                    // rows 0..1023   -> q
  trans_conv_w<<<dim3(32, 32), dim3(32, 8), 0, stream>>>(Wk, wt + 1024 * 1024);      // rows 1024..2047-> k
  trans_conv_w<<<dim3(32, 32), dim3(32, 8), 0, stream>>>(Wv, wt + 2 * 1024 * 1024);  // rows 2048..3071-> v
  concat_bias<<<12, 256, 0, stream>>>(bq, bk, bv, bc);

  // 2. fused QKV projection: [8192,1024] x [3072,1024]^T -> qkv bf16 [8192,3072] (+bias)
  gemm_bt<true, true><<<dim3(24, 64, 1), 256, 0, stream>>>(
      xb, 1024, 0LL, wt, 1024, 0LL, (void*)qkv, 3072, 0LL, bc, 1024, 1.0f);

  // 3. V transpose for BT-form PV
  trans_v<<<dim3(64, 32, 4), dim3(32, 8), 0, stream>>>(qkv, vT);

  // 4. scores = q @ k^T / 32, fp32 into sc  (per batch, z=4)
  gemm_bt<false, false><<<dim3(16, 16, 4), 256, 0, stream>>>(
      qkv, 3072, 2048LL * 3072, qkv + 1024, 3072, 2048LL * 3072,
      (void*)sc, 2048, 2048LL * 2048, nullptr, 1024, 0.03125f);

  // 5. row softmax, P bf16 written in place (row pitch 4096 bf16 elems)
  softmax_rows<<<8192, 256, 0, stream>>>(sc);

  // 6. out = P @ V: A = P bf16 (lda 4096), B = vT  -> fp32 out
  gemm_bt<false, false><<<dim3(8, 16, 4), 256, 0, stream>>>(
      (const u16*)sc, 4096, 2048LL * 4096, vT, 2048, 1024LL * 2048,
      (void*)out, 1024, 2048LL * 1024, nullptr, 2048, 1.0f);
}

// Round 2
// 334.651 us; speedup vs baseline: 1.0205x; 1.0205x over previous
//
#include <hip/hip_runtime.h>
#include <hip/hip_bf16.h>
#include <stdint.h>

// KQV_28956669510232: out = softmax((x@Wq)(x@Wk)^T / 32, axis=keys) @ (x@Wv)
// B=4, S=2048, D=1024, fp32 in/out. bf16 MFMA GEMMs, materialized scores.
//
// R2: gemm_bt switched to 32x32x16 MFMA (fewer issue slots, higher ceiling)
//     + XOR-swizzled LDS (kills the 6.3M bank-conflict cycles R1 measured).
//
// ws layout (~150 MB):
//   xb     bf16 [8192][1024]          @ 0         (16 MB)
//   wt     bf16 [3072][1024] (W^T)    @ 16777216  (6 MB)   rows: q,k,v
//   bc     f32  [3072]                @ 23068672
//   qkv    bf16 [8192][3072]          @ 23080960  (48 MB)
//   vT     bf16 [4][1024][2048]       @ 73412608  (16 MB)
//   sc     f32  [4][2048][2048]       @ 90189824  (64 MB)  -> P bf16 in-place, pitch 4096

typedef unsigned short u16;
typedef __bf16 bf16x8 __attribute__((ext_vector_type(8)));
typedef float  f32x16 __attribute__((ext_vector_type(16)));
typedef u16    u16x4  __attribute__((ext_vector_type(4)));
typedef u16    u16x8  __attribute__((ext_vector_type(8)));

__device__ __forceinline__ u16 f2bf(float f) {
  union { float f; uint32_t u; } v; v.f = f;
  uint32_t r = v.u + 0x7fffu + ((v.u >> 16) & 1u);   // RNE
  return (u16)(r >> 16);
}

#define GLD_LDS16(gp, lp) __builtin_amdgcn_global_load_lds(                   \
    (const __attribute__((address_space(1))) void*)(gp),                      \
    (__attribute__((address_space(3))) void*)(lp), 16, 0, 0)

// ---------------- converts ----------------

__global__ __launch_bounds__(256) void conv_x(const float* __restrict__ in,
                                              u16* __restrict__ out, int n) {
  int i = (blockIdx.x * 256 + threadIdx.x) * 4;
  if (i >= n) return;
  float4 v = *(const float4*)(in + i);
  u16x4 o; o.x = f2bf(v.x); o.y = f2bf(v.y); o.z = f2bf(v.z); o.w = f2bf(v.w);
  *(u16x4*)(out + i) = o;
}

// W [1024][1024] f32 row-major -> Wt [1024][1024] bf16 with Wt[e][d] = W[d][e]
__global__ __launch_bounds__(256) void trans_conv_w(const float* __restrict__ W,
                                                    u16* __restrict__ Wt) {
  __shared__ float t[32][33];
  int e0 = blockIdx.x * 32, d0 = blockIdx.y * 32;
  #pragma unroll
  for (int i = 0; i < 4; ++i)
    t[threadIdx.y + i * 8][threadIdx.x] =
        W[(size_t)(d0 + threadIdx.y + i * 8) * 1024 + e0 + threadIdx.x];
  __syncthreads();
  #pragma unroll
  for (int i = 0; i < 4; ++i)
    Wt[(size_t)(e0 + threadIdx.y + i * 8) * 1024 + d0 + threadIdx.x] =
        f2bf(t[threadIdx.x][threadIdx.y + i * 8]);
}

__global__ __launch_bounds__(256) void concat_bias(const float* __restrict__ bq,
                                                   const float* __restrict__ bk,
                                                   const float* __restrict__ bv,
                                                   float* __restrict__ bc) {
  int i = blockIdx.x * 256 + threadIdx.x;
  if (i >= 3072) return;
  bc[i] = (i < 1024) ? bq[i] : (i < 2048 ? bk[i - 1024] : bv[i - 2048]);
}

// v part of qkv [b*2048+s][2048+e] -> vT[b][e][s]
__global__ __launch_bounds__(256) void trans_v(const u16* __restrict__ qkv,
                                               u16* __restrict__ vT) {
  __shared__ u16 t[32][33];
  int b = blockIdx.z;
  int s0 = blockIdx.x * 32, e0 = blockIdx.y * 32;
  const u16* src = qkv + (size_t)b * 2048 * 3072 + 2048;
  u16* dst = vT + (size_t)b * 1024 * 2048;
  #pragma unroll
  for (int i = 0; i < 4; ++i)
    t[threadIdx.y + i * 8][threadIdx.x] =
        src[(size_t)(s0 + threadIdx.y + i * 8) * 3072 + e0 + threadIdx.x];
  __syncthreads();
  #pragma unroll
  for (int i = 0; i < 4; ++i)
    dst[(size_t)(e0 + threadIdx.y + i * 8) * 2048 + s0 + threadIdx.x] =
        t[threadIdx.x][threadIdx.y + i * 8];
}

// ---------------- BT GEMM: C[m][n] = scale * sum_k A[m][k]*B[n][k] (+bias[n]) --------
// 128x128 tile, BK=32, 256 threads = 4 waves (2x2 of 64x64), 32x32x16 bf16 MFMA.
// LDS XOR swizzle: 16B chunk c of row r stored at chunk position c ^ (r&3).
// global_load_lds writes lane l at base + l*16, so the swizzle is realized by
// permuting the global SOURCE chunk per lane: src chunk = (l&3) ^ ((l>>2)&3).

template <bool OUT_BF16, bool BIAS>
__global__ __launch_bounds__(256)
void gemm_bt(const u16* __restrict__ A, int lda, long long sA,
             const u16* __restrict__ B, int ldb, long long sB,
             void* __restrict__ C, int ldc, long long sC,
             const float* __restrict__ bias, int K, float scale) {
  __shared__ u16 As[128 * 32];
  __shared__ u16 Bs[128 * 32];
  const int lane = threadIdx.x & 63;
  const int wv = threadIdx.x >> 6;

  const u16* Ab = A + (size_t)blockIdx.z * sA + (size_t)blockIdx.y * 128 * lda;
  const u16* Bb = B + (size_t)blockIdx.z * sB + (size_t)blockIdx.x * 128 * ldb;

  const int srow = lane >> 2;                              // staging row within 16
  const int scol = (((lane & 3) ^ ((lane >> 2) & 3)) * 8); // swizzled source chunk
  const int r32 = lane & 31;                               // MFMA row/col within 32
  const int half = lane >> 5;                              // k-half selector
  const int cxor = lane & 3;                               // == row&3 for frag reads
  const int wm = (wv >> 1) * 64;                           // wave tile origin
  const int wn = (wv & 1) * 64;

  f32x16 acc[2][2];
  #pragma unroll
  for (int i = 0; i < 2; ++i)
    #pragma unroll
    for (int j = 0; j < 2; ++j) acc[i][j] = (f32x16)0.0f;

  for (int k0 = 0; k0 < K; k0 += 32) {
    #pragma unroll
    for (int i = 0; i < 2; ++i) {
      int r = wv * 32 + i * 16;  // wave-uniform
      GLD_LDS16(Ab + (size_t)(r + srow) * lda + k0 + scol, As + r * 32);
      GLD_LDS16(Bb + (size_t)(r + srow) * ldb + k0 + scol, Bs + r * 32);
    }
    __syncthreads();

    // A[row=lane&31][k=half*8+j] per 32x32x16 operand layout; chunk swizzled.
    bf16x8 af[2][2], bfr[2][2];
    #pragma unroll
    for (int i = 0; i < 2; ++i)
      #pragma unroll
      for (int t = 0; t < 2; ++t) {
        int c = (t * 2 + half) ^ cxor;
        af[i][t]  = *(const bf16x8*)(As + (wm + i * 32 + r32) * 32 + c * 8);
        bfr[i][t] = *(const bf16x8*)(Bs + (wn + i * 32 + r32) * 32 + c * 8);
      }
    #pragma unroll
    for (int i = 0; i < 2; ++i)
      #pragma unroll
      for (int j = 0; j < 2; ++j)
        #pragma unroll
        for (int t = 0; t < 2; ++t)
          acc[i][j] = __builtin_amdgcn_mfma_f32_32x32x16_bf16(
              af[i][t], bfr[j][t], acc[i][j], 0, 0, 0);
    __syncthreads();
  }

  // C/D layout (32x32): col = lane&31, row = (e&3) + 8*(e>>2) + 4*(lane>>5)
  const int ccol0 = blockIdx.x * 128 + wn + r32;
  const int crow0 = blockIdx.y * 128 + wm + 4 * half;
  u16* Cb = (u16*)C + (size_t)blockIdx.z * sC;
  float* Cf = (float*)C + (size_t)blockIdx.z * sC;
  #pragma unroll
  for (int i = 0; i < 2; ++i) {
    #pragma unroll
    for (int e = 0; e < 16; ++e) {
      int m = crow0 + i * 32 + (e & 3) + 8 * (e >> 2);
      #pragma unroll
      for (int j = 0; j < 2; ++j) {
        int n = ccol0 + j * 32;
        float v = acc[i][j][e] * scale;
        if (BIAS) v += bias[n];
        if (OUT_BF16) Cb[(size_t)m * ldc + n] = f2bf(v);
        else          Cf[(size_t)m * ldc + n] = v;
      }
    }
  }
}

// ---------------- softmax over rows of 2048 f32, write bf16 P in place -------------

__global__ __launch_bounds__(256) void softmax_rows(float* __restrict__ S) {
  __shared__ float red[4];
  const int t = threadIdx.x;
  const int lane = t & 63, wv = t >> 6;
  float* row = S + (size_t)blockIdx.x * 2048;
  const float4* rv = (const float4*)row;
  float4 a = rv[t * 2], b = rv[t * 2 + 1];
  float v[8] = {a.x, a.y, a.z, a.w, b.x, b.y, b.z, b.w};
  float m = v[0];
  #pragma unroll
  for (int j = 1; j < 8; ++j) m = fmaxf(m, v[j]);
  #pragma unroll
  for (int off = 32; off > 0; off >>= 1) m = fmaxf(m, __shfl_down(m, off));
  if (lane == 0) red[wv] = m;
  __syncthreads();
  m = fmaxf(fmaxf(red[0], red[1]), fmaxf(red[2], red[3]));
  __syncthreads();
  float e[8], s = 0.f;
  #pragma unroll
  for (int j = 0; j < 8; ++j) { e[j] = exp2f((v[j] - m) * 1.44269504f); s += e[j]; }
  #pragma unroll
  for (int off = 32; off > 0; off >>= 1) s += __shfl_down(s, off);
  if (lane == 0) red[wv] = s;
  __syncthreads();
  s = red[0] + red[1] + red[2] + red[3];
  float inv = 1.0f / s;
  u16x8 w;
  #pragma unroll
  for (int j = 0; j < 8; ++j) w[j] = f2bf(e[j] * inv);
  ((u16x8*)row)[t] = w;   // all reads happened before the barriers above
}

// ---------------- launch ----------------

extern "C" void kernel_launch(void* const* d_in, const int* in_sizes, int n_in,
                              void* d_out, int out_size, void* d_ws, size_t ws_size,
                              hipStream_t stream) {
  const float* x  = (const float*)d_in[0];
  const float* Wk = (const float*)d_in[1];
  const float* bk = (const float*)d_in[2];
  const float* Wq = (const float*)d_in[3];
  const float* bq = (const float*)d_in[4];
  const float* Wv = (const float*)d_in[5];
  const float* bv = (const float*)d_in[6];
  float* out = (float*)d_out;

  char* ws = (char*)d_ws;
  u16*   xb  = (u16*)(ws + 0);
  u16*   wt  = (u16*)(ws + 16777216);
  float* bc  = (float*)(ws + 23068672);
  u16*   qkv = (u16*)(ws + 23080960);
  u16*   vT  = (u16*)(ws + 73412608);
  float* sc  = (float*)(ws + 90189824);
  (void)in_sizes; (void)n_in; (void)out_size; (void)ws_size;

  // 1. convert inputs to bf16 (W transposed so every GEMM is BT-form)
  conv_x<<<8192, 256, 0, stream>>>(x, xb, 8388608);
  trans_conv_w<<<dim3(32, 32), dim3(32, 8), 0, stream>>>(Wq, wt);
  trans_conv_w<<<dim3(32, 32), dim3(32, 8), 0, stream>>>(Wk, wt + 1024 * 1024);
  trans_conv_w<<<dim3(32, 32), dim3(32, 8), 0, stream>>>(Wv, wt + 2 * 1024 * 1024);
  concat_bias<<<12, 256, 0, stream>>>(bq, bk, bv, bc);

  // 2. fused QKV projection: [8192,1024] x [3072,1024]^T -> qkv bf16 (+bias)
  gemm_bt<true, true><<<dim3(24, 64, 1), 256, 0, stream>>>(
      xb, 1024, 0LL, wt, 1024, 0LL, (void*)qkv, 3072, 0LL, bc, 1024, 1.0f);

  // 3. V transpose for BT-form PV
  trans_v<<<dim3(64, 32, 4), dim3(32, 8), 0, stream>>>(qkv, vT);

  // 4. scores = q @ k^T / 32, fp32 into sc (per batch)
  gemm_bt<false, false><<<dim3(16, 16, 4), 256, 0, stream>>>(
      qkv, 3072, 2048LL * 3072, qkv + 1024, 3072, 2048LL * 3072,
      (void*)sc, 2048, 2048LL * 2048, nullptr, 1024, 0.03125f);

  // 5. row softmax, P bf16 written in place (row pitch 4096 bf16 elems)
  softmax_rows<<<8192, 256, 0, stream>>>(sc);

  // 6. out = P @ V: A = P bf16 (lda 4096), B = vT -> fp32 out
  gemm_bt<false, false><<<dim3(8, 16, 4), 256, 0, stream>>>(
      (const u16*)sc, 4096, 2048LL * 4096, vT, 2048, 1024LL * 2048,
      (void*)out, 1024, 2048LL * 1024, nullptr, 2048, 1.0f);
}

// Round 3
// 287.950 us; speedup vs baseline: 1.1860x; 1.1622x over previous
//
#include <hip/hip_runtime.h>
#include <hip/hip_bf16.h>
#include <stdint.h>

// KQV_28956669510232: out = softmax((x@Wq)(x@Wk)^T / 32, axis=keys) @ (x@Wv)
// B=4, S=2048, D=1024, fp32 in/out. bf16 MFMA GEMMs, materialized scores.
//
// R3: gemm_bt BK=64 (half the barrier drains) + XOR-8 LDS swizzle on 128 B
//     rows (chunk c of row r at c^(r&7)) -> fragment ds_read_b128 and staging
//     writes both exactly bank-uniform (8 lanes per 4-bank column, 8-cyc min).
//     R2's c^(r&3) swizzle on 64 B rows hit only 16/32 banks (18.9M conflict
//     cycles measured) -- theory error, corrected by worked bank arithmetic.
//
// ws layout (~150 MB):
//   xb     bf16 [8192][1024]          @ 0         (16 MB)
//   wt     bf16 [3072][1024] (W^T)    @ 16777216  (6 MB)   rows: q,k,v
//   bc     f32  [3072]                @ 23068672
//   qkv    bf16 [8192][3072]          @ 23080960  (48 MB)
//   vT     bf16 [4][1024][2048]       @ 73412608  (16 MB)
//   sc     f32  [4][2048][2048]       @ 90189824  (64 MB)  -> P bf16 in-place, pitch 4096

typedef unsigned short u16;
typedef __bf16 bf16x8 __attribute__((ext_vector_type(8)));
typedef float  f32x16 __attribute__((ext_vector_type(16)));
typedef u16    u16x4  __attribute__((ext_vector_type(4)));
typedef u16    u16x8  __attribute__((ext_vector_type(8)));

__device__ __forceinline__ u16 f2bf(float f) {
  union { float f; uint32_t u; } v; v.f = f;
  uint32_t r = v.u + 0x7fffu + ((v.u >> 16) & 1u);   // RNE
  return (u16)(r >> 16);
}

#define GLD_LDS16(gp, lp) __builtin_amdgcn_global_load_lds(                   \
    (const __attribute__((address_space(1))) void*)(gp),                      \
    (__attribute__((address_space(3))) void*)(lp), 16, 0, 0)

// ---------------- converts ----------------

__global__ __launch_bounds__(256) void conv_x(const float* __restrict__ in,
                                              u16* __restrict__ out, int n) {
  int i = (blockIdx.x * 256 + threadIdx.x) * 4;
  if (i >= n) return;
  float4 v = *(const float4*)(in + i);
  u16x4 o; o.x = f2bf(v.x); o.y = f2bf(v.y); o.z = f2bf(v.z); o.w = f2bf(v.w);
  *(u16x4*)(out + i) = o;
}

// W [1024][1024] f32 row-major -> Wt [1024][1024] bf16 with Wt[e][d] = W[d][e]
__global__ __launch_bounds__(256) void trans_conv_w(const float* __restrict__ W,
                                                    u16* __restrict__ Wt) {
  __shared__ float t[32][33];
  int e0 = blockIdx.x * 32, d0 = blockIdx.y * 32;
  #pragma unroll
  for (int i = 0; i < 4; ++i)
    t[threadIdx.y + i * 8][threadIdx.x] =
        W[(size_t)(d0 + threadIdx.y + i * 8) * 1024 + e0 + threadIdx.x];
  __syncthreads();
  #pragma unroll
  for (int i = 0; i < 4; ++i)
    Wt[(size_t)(e0 + threadIdx.y + i * 8) * 1024 + d0 + threadIdx.x] =
        f2bf(t[threadIdx.x][threadIdx.y + i * 8]);
}

__global__ __launch_bounds__(256) void concat_bias(const float* __restrict__ bq,
                                                   const float* __restrict__ bk,
                                                   const float* __restrict__ bv,
                                                   float* __restrict__ bc) {
  int i = blockIdx.x * 256 + threadIdx.x;
  if (i >= 3072) return;
  bc[i] = (i < 1024) ? bq[i] : (i < 2048 ? bk[i - 1024] : bv[i - 2048]);
}

// v part of qkv [b*2048+s][2048+e] -> vT[b][e][s]
__global__ __launch_bounds__(256) void trans_v(const u16* __restrict__ qkv,
                                               u16* __restrict__ vT) {
  __shared__ u16 t[32][33];
  int b = blockIdx.z;
  int s0 = blockIdx.x * 32, e0 = blockIdx.y * 32;
  const u16* src = qkv + (size_t)b * 2048 * 3072 + 2048;
  u16* dst = vT + (size_t)b * 1024 * 2048;
  #pragma unroll
  for (int i = 0; i < 4; ++i)
    t[threadIdx.y + i * 8][threadIdx.x] =
        src[(size_t)(s0 + threadIdx.y + i * 8) * 3072 + e0 + threadIdx.x];
  __syncthreads();
  #pragma unroll
  for (int i = 0; i < 4; ++i)
    dst[(size_t)(e0 + threadIdx.y + i * 8) * 2048 + s0 + threadIdx.x] =
        t[threadIdx.x][threadIdx.y + i * 8];
}

// ---------------- BT GEMM: C[m][n] = scale * sum_k A[m][k]*B[n][k] (+bias[n]) --------
// 128x128 tile, BK=64, 256 threads = 4 waves (2x2 of 64x64), 32x32x16 bf16 MFMA.
// LDS rows are 128 B (64 u16 = 8 chunks of 16 B). XOR-8 swizzle: chunk c of row
// r is stored at chunk position c ^ (r&7).
//   Staging: global_load_lds puts lane l at base + l*16 -> physical (row l>>3,
//   chunk l&7); we read global chunk (l&7)^(l>>3) so the logical layout is the
//   swizzle above. Each 8-lane group still covers one contiguous 128 B global
//   segment (lane-permuted), so coalescing is preserved.
//   Fragment reads: row = ..+ (lane&31), logical chunk c = t*2 + (lane>>5);
//   physical chunk = c ^ (lane&7) -> per b128 read, lanes spread uniformly
//   8-per-chunk-column over all 32 banks: conflict-free.

template <bool OUT_BF16, bool BIAS>
__global__ __launch_bounds__(256)
void gemm_bt(const u16* __restrict__ A, int lda, long long sA,
             const u16* __restrict__ B, int ldb, long long sB,
             void* __restrict__ C, int ldc, long long sC,
             const float* __restrict__ bias, int K, float scale) {
  __shared__ u16 As[128 * 64];
  __shared__ u16 Bs[128 * 64];
  const int lane = threadIdx.x & 63;
  const int wv = threadIdx.x >> 6;

  const u16* Ab = A + (size_t)blockIdx.z * sA + (size_t)blockIdx.y * 128 * lda;
  const u16* Bb = B + (size_t)blockIdx.z * sB + (size_t)blockIdx.x * 128 * ldb;

  const int srow = lane >> 3;                      // staging row within 8-row group
  const int scol = ((lane & 7) ^ (lane >> 3)) * 8; // swizzled global source chunk
  const int r32 = lane & 31;                       // MFMA row/col within 32
  const int half = lane >> 5;                      // k-half selector
  const int rx = lane & 7;                         // row&7 for fragment chunk xor
  const int wm = (wv >> 1) * 64;                   // wave tile origin
  const int wn = (wv & 1) * 64;

  f32x16 acc[2][2];
  #pragma unroll
  for (int i = 0; i < 2; ++i)
    #pragma unroll
    for (int j = 0; j < 2; ++j) acc[i][j] = (f32x16)0.0f;

  for (int k0 = 0; k0 < K; k0 += 64) {
    // stage A and B 128x64 tiles: each wave covers 32 rows (4 calls x 8 rows)
    #pragma unroll
    for (int i = 0; i < 4; ++i) {
      int r = wv * 32 + i * 8;  // wave-uniform, multiple of 8
      GLD_LDS16(Ab + (size_t)(r + srow) * lda + k0 + scol, As + r * 64);
      GLD_LDS16(Bb + (size_t)(r + srow) * ldb + k0 + scol, Bs + r * 64);
    }
    __syncthreads();

    // A[row=lane&31][k = t*16 + half*8 + j] -> logical chunk t*2+half, XOR rx.
    bf16x8 af[2][4], bfr[2][4];
    #pragma unroll
    for (int i = 0; i < 2; ++i)
      #pragma unroll
      for (int t = 0; t < 4; ++t) {
        int pc = ((t * 2 + half) ^ rx) * 8;
        af[i][t]  = *(const bf16x8*)(As + (wm + i * 32 + r32) * 64 + pc);
        bfr[i][t] = *(const bf16x8*)(Bs + (wn + i * 32 + r32) * 64 + pc);
      }
    #pragma unroll
    for (int i = 0; i < 2; ++i)
      #pragma unroll
      for (int j = 0; j < 2; ++j)
        #pragma unroll
        for (int t = 0; t < 4; ++t)
          acc[i][j] = __builtin_amdgcn_mfma_f32_32x32x16_bf16(
              af[i][t], bfr[j][t], acc[i][j], 0, 0, 0);
    __syncthreads();
  }

  // C/D layout (32x32): col = lane&31, row = (e&3) + 8*(e>>2) + 4*(lane>>5)
  const int ccol0 = blockIdx.x * 128 + wn + r32;
  const int crow0 = blockIdx.y * 128 + wm + 4 * half;
  u16* Cb = (u16*)C + (size_t)blockIdx.z * sC;
  float* Cf = (float*)C + (size_t)blockIdx.z * sC;
  #pragma unroll
  for (int i = 0; i < 2; ++i) {
    #pragma unroll
    for (int e = 0; e < 16; ++e) {
      int m = crow0 + i * 32 + (e & 3) + 8 * (e >> 2);
      #pragma unroll
      for (int j = 0; j < 2; ++j) {
        int n = ccol0 + j * 32;
        float v = acc[i][j][e] * scale;
        if (BIAS) v += bias[n];
        if (OUT_BF16) Cb[(size_t)m * ldc + n] = f2bf(v);
        else          Cf[(size_t)m * ldc + n] = v;
      }
    }
  }
}

// ---------------- softmax over rows of 2048 f32, write bf16 P in place -------------

__global__ __launch_bounds__(256) void softmax_rows(float* __restrict__ S) {
  __shared__ float red[4];
  const int t = threadIdx.x;
  const int lane = t & 63, wv = t >> 6;
  float* row = S + (size_t)blockIdx.x * 2048;
  const float4* rv = (const float4*)row;
  float4 a = rv[t * 2], b = rv[t * 2 + 1];
  float v[8] = {a.x, a.y, a.z, a.w, b.x, b.y, b.z, b.w};
  float m = v[0];
  #pragma unroll
  for (int j = 1; j < 8; ++j) m = fmaxf(m, v[j]);
  #pragma unroll
  for (int off = 32; off > 0; off >>= 1) m = fmaxf(m, __shfl_down(m, off));
  if (lane == 0) red[wv] = m;
  __syncthreads();
  m = fmaxf(fmaxf(red[0], red[1]), fmaxf(red[2], red[3]));
  __syncthreads();
  float e[8], s = 0.f;
  #pragma unroll
  for (int j = 0; j < 8; ++j) { e[j] = exp2f((v[j] - m) * 1.44269504f); s += e[j]; }
  #pragma unroll
  for (int off = 32; off > 0; off >>= 1) s += __shfl_down(s, off);
  if (lane == 0) red[wv] = s;
  __syncthreads();
  s = red[0] + red[1] + red[2] + red[3];
  float inv = 1.0f / s;
  u16x8 w;
  #pragma unroll
  for (int j = 0; j < 8; ++j) w[j] = f2bf(e[j] * inv);
  ((u16x8*)row)[t] = w;   // all reads happened before the barriers above
}

// ---------------- launch ----------------

extern "C" void kernel_launch(void* const* d_in, const int* in_sizes, int n_in,
                              void* d_out, int out_size, void* d_ws, size_t ws_size,
                              hipStream_t stream) {
  const float* x  = (const float*)d_in[0];
  const float* Wk = (const float*)d_in[1];
  const float* bk = (const float*)d_in[2];
  const float* Wq = (const float*)d_in[3];
  const float* bq = (const float*)d_in[4];
  const float* Wv = (const float*)d_in[5];
  const float* bv = (const float*)d_in[6];
  float* out = (float*)d_out;

  char* ws = (char*)d_ws;
  u16*   xb  = (u16*)(ws + 0);
  u16*   wt  = (u16*)(ws + 16777216);
  float* bc  = (float*)(ws + 23068672);
  u16*   qkv = (u16*)(ws + 23080960);
  u16*   vT  = (u16*)(ws + 73412608);
  float* sc  = (float*)(ws + 90189824);
  (void)in_sizes; (void)n_in; (void)out_size; (void)ws_size;

  // 1. convert inputs to bf16 (W transposed so every GEMM is BT-form)
  conv_x<<<8192, 256, 0, stream>>>(x, xb, 8388608);
  trans_conv_w<<<dim3(32, 32), dim3(32, 8), 0, stream>>>(Wq, wt);
  trans_conv_w<<<dim3(32, 32), dim3(32, 8), 0, stream>>>(Wk, wt + 1024 * 1024);
  trans_conv_w<<<dim3(32, 32), dim3(32, 8), 0, stream>>>(Wv, wt + 2 * 1024 * 1024);
  concat_bias<<<12, 256, 0, stream>>>(bq, bk, bv, bc);

  // 2. fused QKV projection: [8192,1024] x [3072,1024]^T -> qkv bf16 (+bias)
  gemm_bt<true, true><<<dim3(24, 64, 1), 256, 0, stream>>>(
      xb, 1024, 0LL, wt, 1024, 0LL, (void*)qkv, 3072, 0LL, bc, 1024, 1.0f);

  // 3. V transpose for BT-form PV
  trans_v<<<dim3(64, 32, 4), dim3(32, 8), 0, stream>>>(qkv, vT);

  // 4. scores = q @ k^T / 32, fp32 into sc (per batch)
  gemm_bt<false, false><<<dim3(16, 16, 4), 256, 0, stream>>>(
      qkv, 3072, 2048LL * 3072, qkv + 1024, 3072, 2048LL * 3072,
      (void*)sc, 2048, 2048LL * 2048, nullptr, 1024, 0.03125f);

  // 5. row softmax, P bf16 written in place (row pitch 4096 bf16 elems)
  softmax_rows<<<8192, 256, 0, stream>>>(sc);

  // 6. out = P @ V: A = P bf16 (lda 4096), B = vT -> fp32 out
  gemm_bt<false, false><<<dim3(8, 16, 4), 256, 0, stream>>>(
      (const u16*)sc, 4096, 2048LL * 4096, vT, 2048, 1024LL * 2048,
      (void*)out, 1024, 2048LL * 1024, nullptr, 2048, 1.0f);
}

// Round 4
// 275.524 us; speedup vs baseline: 1.2395x; 1.0451x over previous
//
#include <hip/hip_runtime.h>
#include <hip/hip_bf16.h>
#include <stdint.h>

// KQV_28956669510232: out = softmax((x@Wq)(x@Wk)^T / 32, axis=keys) @ (x@Wv)
// B=4, S=2048, D=1024, fp32 in/out. bf16 MFMA GEMMs, materialized scores.
//
// R4: scores written as bf16 P directly (softmax jitter analysis: bf16 score
//     noise 0.004 * sqrt(sum p^2)=0.022 -> ~9e-5 output noise, safe);
//     softmax operates on bf16 rows; PV GEMM gets a 512-thread variant
//     (8 waves -> 16 waves/CU at its 2-blocks/CU grid); trans_v vectorized;
//     3x trans_conv_w merged into one dispatch.
// R3 note: residual 6.29M SQ_LDS_BANK_CONFLICT = 4 cyc/b128 = m134's b128
//     issue overhead, not address conflicts. QKV is at the m97 plateau.
//
// ws layout (~122 MB):
//   xb     bf16 [8192][1024]          @ 0         (16 MB)
//   wt     bf16 [3072][1024] (W^T)    @ 16777216  (6 MB)   rows: q,k,v
//   bc     f32  [3072]                @ 23068672
//   qkv    bf16 [8192][3072]          @ 23080960  (48 MB)
//   vT     bf16 [4][1024][2048]       @ 73412608  (16 MB)
//   P      bf16 [4][2048][2048]       @ 90189824  (32 MB)  scores -> P in place

typedef unsigned short u16;
typedef __bf16 bf16x8 __attribute__((ext_vector_type(8)));
typedef float  f32x16 __attribute__((ext_vector_type(16)));
typedef u16    u16x4  __attribute__((ext_vector_type(4)));
typedef u16    u16x8  __attribute__((ext_vector_type(8)));

__device__ __forceinline__ u16 f2bf(float f) {
  union { float f; uint32_t u; } v; v.f = f;
  uint32_t r = v.u + 0x7fffu + ((v.u >> 16) & 1u);   // RNE
  return (u16)(r >> 16);
}
__device__ __forceinline__ float bf2f(u16 b) {
  union { uint32_t u; float f; } v; v.u = (uint32_t)b << 16; return v.f;
}

#define GLD_LDS16(gp, lp) __builtin_amdgcn_global_load_lds(                   \
    (const __attribute__((address_space(1))) void*)(gp),                      \
    (__attribute__((address_space(3))) void*)(lp), 16, 0, 0)

// ---------------- converts ----------------

__global__ __launch_bounds__(256) void conv_x(const float* __restrict__ in,
                                              u16* __restrict__ out, int n) {
  int i = (blockIdx.x * 256 + threadIdx.x) * 4;
  if (i >= n) return;
  float4 v = *(const float4*)(in + i);
  u16x4 o; o.x = f2bf(v.x); o.y = f2bf(v.y); o.z = f2bf(v.z); o.w = f2bf(v.w);
  *(u16x4*)(out + i) = o;
}

// W [1024][1024] f32 row-major -> Wt bf16 with Wt[e][d] = W[d][e]; z picks q/k/v
__global__ __launch_bounds__(256) void trans_conv_w3(const float* __restrict__ Wq,
                                                     const float* __restrict__ Wk,
                                                     const float* __restrict__ Wv,
                                                     u16* __restrict__ Wt) {
  __shared__ float t[32][33];
  const float* W = blockIdx.z == 0 ? Wq : (blockIdx.z == 1 ? Wk : Wv);
  u16* dst = Wt + (size_t)blockIdx.z * 1024 * 1024;
  int e0 = blockIdx.x * 32, d0 = blockIdx.y * 32;
  #pragma unroll
  for (int i = 0; i < 4; ++i)
    t[threadIdx.y + i * 8][threadIdx.x] =
        W[(size_t)(d0 + threadIdx.y + i * 8) * 1024 + e0 + threadIdx.x];
  __syncthreads();
  #pragma unroll
  for (int i = 0; i < 4; ++i)
    dst[(size_t)(e0 + threadIdx.y + i * 8) * 1024 + d0 + threadIdx.x] =
        f2bf(t[threadIdx.x][threadIdx.y + i * 8]);
}

__global__ __launch_bounds__(256) void concat_bias(const float* __restrict__ bq,
                                                   const float* __restrict__ bk,
                                                   const float* __restrict__ bv,
                                                   float* __restrict__ bc) {
  int i = blockIdx.x * 256 + threadIdx.x;
  if (i >= 3072) return;
  bc[i] = (i < 1024) ? bq[i] : (i < 2048 ? bk[i - 1024] : bv[i - 2048]);
}

// v part of qkv [b*2048+s][2048+e] -> vT[b][e][s]; 64x64 tiles, u16x8 both sides
__global__ __launch_bounds__(256) void trans_v(const u16* __restrict__ qkv,
                                               u16* __restrict__ vT) {
  __shared__ u16 t[64][72];
  int b = blockIdx.z;
  int s0 = blockIdx.x * 64, e0 = blockIdx.y * 64;
  const u16* src = qkv + (size_t)b * 2048 * 3072 + 2048;
  u16* dst = vT + (size_t)b * 1024 * 2048;
  int tx = threadIdx.x & 7, ty = threadIdx.x >> 3;   // tx: 16B chunk, ty: 0..31
  #pragma unroll
  for (int rr = 0; rr < 64; rr += 32)
    *(u16x8*)&t[ty + rr][tx * 8] =
        *(const u16x8*)(src + (size_t)(s0 + ty + rr) * 3072 + e0 + tx * 8);
  __syncthreads();
  #pragma unroll
  for (int rr = 0; rr < 64; rr += 32) {
    int er = ty + rr;
    u16x8 o;
    #pragma unroll
    for (int j = 0; j < 8; ++j) o[j] = t[tx * 8 + j][er];
    *(u16x8*)(dst + (size_t)(e0 + er) * 2048 + s0 + tx * 8) = o;
  }
}

// ---------------- BT GEMM: C[m][n] = scale * sum_k A[m][k]*B[n][k] (+bias[n]) --------
// 128x128 tile, BK=64, 256 threads = 4 waves (2x2 of 64x64), 32x32x16 bf16 MFMA.
// XOR-8 LDS swizzle on 128 B rows: chunk c of row r at c^(r&7); staging realizes
// it by permuting the global source chunk (coalescing preserved within 128 B).

template <bool OUT_BF16, bool BIAS>
__global__ __launch_bounds__(256)
void gemm_bt(const u16* __restrict__ A, int lda, long long sA,
             const u16* __restrict__ B, int ldb, long long sB,
             void* __restrict__ C, int ldc, long long sC,
             const float* __restrict__ bias, int K, float scale) {
  __shared__ u16 As[128 * 64];
  __shared__ u16 Bs[128 * 64];
  const int lane = threadIdx.x & 63;
  const int wv = threadIdx.x >> 6;

  const u16* Ab = A + (size_t)blockIdx.z * sA + (size_t)blockIdx.y * 128 * lda;
  const u16* Bb = B + (size_t)blockIdx.z * sB + (size_t)blockIdx.x * 128 * ldb;

  const int srow = lane >> 3;
  const int scol = ((lane & 7) ^ (lane >> 3)) * 8;
  const int r32 = lane & 31;
  const int half = lane >> 5;
  const int rx = lane & 7;
  const int wm = (wv >> 1) * 64;
  const int wn = (wv & 1) * 64;

  f32x16 acc[2][2];
  #pragma unroll
  for (int i = 0; i < 2; ++i)
    #pragma unroll
    for (int j = 0; j < 2; ++j) acc[i][j] = (f32x16)0.0f;

  for (int k0 = 0; k0 < K; k0 += 64) {
    #pragma unroll
    for (int i = 0; i < 4; ++i) {
      int r = wv * 32 + i * 8;  // wave-uniform
      GLD_LDS16(Ab + (size_t)(r + srow) * lda + k0 + scol, As + r * 64);
      GLD_LDS16(Bb + (size_t)(r + srow) * ldb + k0 + scol, Bs + r * 64);
    }
    __syncthreads();

    bf16x8 af[2][4], bfr[2][4];
    #pragma unroll
    for (int i = 0; i < 2; ++i)
      #pragma unroll
      for (int t = 0; t < 4; ++t) {
        int pc = ((t * 2 + half) ^ rx) * 8;
        af[i][t]  = *(const bf16x8*)(As + (wm + i * 32 + r32) * 64 + pc);
        bfr[i][t] = *(const bf16x8*)(Bs + (wn + i * 32 + r32) * 64 + pc);
      }
    #pragma unroll
    for (int i = 0; i < 2; ++i)
      #pragma unroll
      for (int j = 0; j < 2; ++j)
        #pragma unroll
        for (int t = 0; t < 4; ++t)
          acc[i][j] = __builtin_amdgcn_mfma_f32_32x32x16_bf16(
              af[i][t], bfr[j][t], acc[i][j], 0, 0, 0);
    __syncthreads();
  }

  // C/D layout (32x32): col = lane&31, row = (e&3) + 8*(e>>2) + 4*(lane>>5)
  const int ccol0 = blockIdx.x * 128 + wn + r32;
  const int crow0 = blockIdx.y * 128 + wm + 4 * half;
  u16* Cb = (u16*)C + (size_t)blockIdx.z * sC;
  float* Cf = (float*)C + (size_t)blockIdx.z * sC;
  #pragma unroll
  for (int i = 0; i < 2; ++i) {
    #pragma unroll
    for (int e = 0; e < 16; ++e) {
      int m = crow0 + i * 32 + (e & 3) + 8 * (e >> 2);
      #pragma unroll
      for (int j = 0; j < 2; ++j) {
        int n = ccol0 + j * 32;
        float v = acc[i][j][e] * scale;
        if (BIAS) v += bias[n];
        if (OUT_BF16) Cb[(size_t)m * ldc + n] = f2bf(v);
        else          Cf[(size_t)m * ldc + n] = v;
      }
    }
  }
}

// 512-thread variant (8 waves, wave grid 2m x 4n, wave tile 64x32) for the
// PV GEMM whose grid is only 512 blocks (2/CU): doubles waves/CU 8 -> 16.
__global__ __launch_bounds__(512)
void gemm_bt8(const u16* __restrict__ A, int lda, long long sA,
              const u16* __restrict__ B, int ldb, long long sB,
              float* __restrict__ C, int ldc, long long sC,
              int K, float scale) {
  __shared__ u16 As[128 * 64];
  __shared__ u16 Bs[128 * 64];
  const int lane = threadIdx.x & 63;
  const int wv = threadIdx.x >> 6;          // 0..7

  const u16* Ab = A + (size_t)blockIdx.z * sA + (size_t)blockIdx.y * 128 * lda;
  const u16* Bb = B + (size_t)blockIdx.z * sB + (size_t)blockIdx.x * 128 * ldb;

  const int srow = lane >> 3;
  const int scol = ((lane & 7) ^ (lane >> 3)) * 8;
  const int r32 = lane & 31;
  const int half = lane >> 5;
  const int rx = lane & 7;
  const int wm = (wv >> 2) * 64;            // 2 wave-rows
  const int wn = (wv & 3) * 32;             // 4 wave-cols

  f32x16 acc[2];
  acc[0] = (f32x16)0.0f; acc[1] = (f32x16)0.0f;

  for (int k0 = 0; k0 < K; k0 += 64) {
    #pragma unroll
    for (int i = 0; i < 2; ++i) {
      int r = wv * 16 + i * 8;  // 8 waves x 16 rows = 128
      GLD_LDS16(Ab + (size_t)(r + srow) * lda + k0 + scol, As + r * 64);
      GLD_LDS16(Bb + (size_t)(r + srow) * ldb + k0 + scol, Bs + r * 64);
    }
    __syncthreads();

    bf16x8 af[2][4], bfr[4];
    #pragma unroll
    for (int t = 0; t < 4; ++t) {
      int pc = ((t * 2 + half) ^ rx) * 8;
      af[0][t] = *(const bf16x8*)(As + (wm + r32) * 64 + pc);
      af[1][t] = *(const bf16x8*)(As + (wm + 32 + r32) * 64 + pc);
      bfr[t]   = *(const bf16x8*)(Bs + (wn + r32) * 64 + pc);
    }
    #pragma unroll
    for (int i = 0; i < 2; ++i)
      #pragma unroll
      for (int t = 0; t < 4; ++t)
        acc[i] = __builtin_amdgcn_mfma_f32_32x32x16_bf16(
            af[i][t], bfr[t], acc[i], 0, 0, 0);
    __syncthreads();
  }

  const int ccol = blockIdx.x * 128 + wn + r32;
  const int crow0 = blockIdx.y * 128 + wm + 4 * half;
  float* Cf = C + (size_t)blockIdx.z * sC;
  #pragma unroll
  for (int i = 0; i < 2; ++i)
    #pragma unroll
    for (int e = 0; e < 16; ++e) {
      int m = crow0 + i * 32 + (e & 3) + 8 * (e >> 2);
      Cf[(size_t)m * ldc + ccol] = acc[i][e] * scale;
    }
}

// ---------------- softmax over bf16 rows of 2048, in place -------------

__global__ __launch_bounds__(256) void softmax_rows(u16* __restrict__ P) {
  __shared__ float red[4];
  const int t = threadIdx.x;
  const int lane = t & 63, wv = t >> 6;
  u16* row = P + (size_t)blockIdx.x * 2048;
  u16x8 w = ((const u16x8*)row)[t];
  float v[8];
  #pragma unroll
  for (int j = 0; j < 8; ++j) v[j] = bf2f(w[j]);
  float m = v[0];
  #pragma unroll
  for (int j = 1; j < 8; ++j) m = fmaxf(m, v[j]);
  #pragma unroll
  for (int off = 32; off > 0; off >>= 1) m = fmaxf(m, __shfl_down(m, off));
  if (lane == 0) red[wv] = m;
  __syncthreads();
  m = fmaxf(fmaxf(red[0], red[1]), fmaxf(red[2], red[3]));
  __syncthreads();
  float e[8], s = 0.f;
  #pragma unroll
  for (int j = 0; j < 8; ++j) { e[j] = exp2f((v[j] - m) * 1.44269504f); s += e[j]; }
  #pragma unroll
  for (int off = 32; off > 0; off >>= 1) s += __shfl_down(s, off);
  if (lane == 0) red[wv] = s;
  __syncthreads();
  s = red[0] + red[1] + red[2] + red[3];
  float inv = 1.0f / s;
  u16x8 o;
  #pragma unroll
  for (int j = 0; j < 8; ++j) o[j] = f2bf(e[j] * inv);
  ((u16x8*)row)[t] = o;
}

// ---------------- launch ----------------

extern "C" void kernel_launch(void* const* d_in, const int* in_sizes, int n_in,
                              void* d_out, int out_size, void* d_ws, size_t ws_size,
                              hipStream_t stream) {
  const float* x  = (const float*)d_in[0];
  const float* Wk = (const float*)d_in[1];
  const float* bk = (const float*)d_in[2];
  const float* Wq = (const float*)d_in[3];
  const float* bq = (const float*)d_in[4];
  const float* Wv = (const float*)d_in[5];
  const float* bv = (const float*)d_in[6];
  float* out = (float*)d_out;

  char* ws = (char*)d_ws;
  u16*   xb  = (u16*)(ws + 0);
  u16*   wt  = (u16*)(ws + 16777216);
  float* bc  = (float*)(ws + 23068672);
  u16*   qkv = (u16*)(ws + 23080960);
  u16*   vT  = (u16*)(ws + 73412608);
  u16*   P   = (u16*)(ws + 90189824);
  (void)in_sizes; (void)n_in; (void)out_size; (void)ws_size;

  // 1. convert inputs to bf16 (W transposed so every GEMM is BT-form)
  conv_x<<<8192, 256, 0, stream>>>(x, xb, 8388608);
  trans_conv_w3<<<dim3(32, 32, 3), dim3(32, 8), 0, stream>>>(Wq, Wk, Wv, wt);
  concat_bias<<<12, 256, 0, stream>>>(bq, bk, bv, bc);

  // 2. fused QKV projection: [8192,1024] x [3072,1024]^T -> qkv bf16 (+bias)
  gemm_bt<true, true><<<dim3(24, 64, 1), 256, 0, stream>>>(
      xb, 1024, 0LL, wt, 1024, 0LL, (void*)qkv, 3072, 0LL, bc, 1024, 1.0f);

  // 3. V transpose for BT-form PV
  trans_v<<<dim3(32, 16, 4), 256, 0, stream>>>(qkv, vT);

  // 4. scores = q @ k^T / 32 -> bf16 P directly (pitch 2048)
  gemm_bt<true, false><<<dim3(16, 16, 4), 256, 0, stream>>>(
      qkv, 3072, 2048LL * 3072, qkv + 1024, 3072, 2048LL * 3072,
      (void*)P, 2048, 2048LL * 2048, nullptr, 1024, 0.03125f);

  // 5. row softmax on bf16 P, in place
  softmax_rows<<<8192, 256, 0, stream>>>(P);

  // 6. out = P @ V (512-thread variant: PV grid is only 2 blocks/CU)
  gemm_bt8<<<dim3(8, 16, 4), 512, 0, stream>>>(
      P, 2048, 2048LL * 2048, vT, 2048, 1024LL * 2048,
      out, 1024, 2048LL * 1024, 2048, 1.0f);
}